// Round 1
// baseline (27.444 us; speedup 1.0000x reference)
//
#include <hip/hip_runtime.h>

// SoftHistogram: x[B=64, N=1000, F=256] fp32 -> out[B, F*K=2048] fp32
// out[b, f*8+k] = mean_n relu(1 - 16*|x[b,n,f] - (k+0.5)/8|)
// With u = 8x - 0.5:  y_k = relu(1 - 2*|u - k|).
//
// Grid: B * (F/16) = 1024 blocks, 256 threads.
// Thread t: fl4 = t&3 (which float4 of the 16-f slice), nsub = t>>2 (n stride 64).
// Wave footprint per load: 16 rows x 64B aligned segments (coalesced).
// Block reduction over 64 nsubs via LDS (row stride 129 floats to break
// the power-of-2 bank pattern), then 128 consecutive fp32 stores per block.

__global__ __launch_bounds__(256) void softhist_kernel(const float* __restrict__ x,
                                                       float* __restrict__ out) {
    constexpr int N = 1000, F = 256, K = 8;
    constexpr int FG = 16;              // f's per block
    constexpr int BPB = F / FG;         // 16 blocks per batch row

    const int bid = blockIdx.x;
    const int b   = bid / BPB;
    const int f0  = (bid % BPB) * FG;

    const int t    = threadIdx.x;
    const int fl4  = t & 3;             // float4 index within the 16-f slice
    const int nsub = t >> 2;            // 0..63

    float acc[4][K];
#pragma unroll
    for (int i = 0; i < 4; ++i)
#pragma unroll
        for (int k = 0; k < K; ++k) acc[i][k] = 0.0f;

    const float* base = x + (b * N) * F + f0 + fl4 * 4;

    for (int n = nsub; n < N; n += 64) {
        const float4 v = *reinterpret_cast<const float4*>(base + n * F);
        const float xs[4] = {v.x, v.y, v.z, v.w};
#pragma unroll
        for (int i = 0; i < 4; ++i) {
            const float u = fmaf(xs[i], 8.0f, -0.5f);
#pragma unroll
            for (int k = 0; k < K; ++k) {
                // y = 1 - 2*|u - k|  (abs folds into fma input modifier)
                const float y = fmaf(-2.0f, fabsf(u - (float)k), 1.0f);
                acc[i][k] += fmaxf(y, 0.0f);
            }
        }
    }

    // LDS reduce across the 64 n-subgroups.
    // part[nsub][col], col = fl4*32 + i*8 + k in [0,128); row stride 129.
    __shared__ float part[64 * 129];
#pragma unroll
    for (int i = 0; i < 4; ++i)
#pragma unroll
        for (int k = 0; k < K; ++k)
            part[nsub * 129 + fl4 * 32 + i * 8 + k] = acc[i][k];
    __syncthreads();

    if (t < FG * K) {  // 128 output columns per block
        float s = 0.0f;
#pragma unroll
        for (int ns = 0; ns < 64; ++ns) s += part[ns * 129 + t];
        out[(b * F + f0) * K + t] = s * (1.0f / (float)N);
    }
}

extern "C" void kernel_launch(void* const* d_in, const int* in_sizes, int n_in,
                              void* d_out, int out_size, void* d_ws, size_t ws_size,
                              hipStream_t stream) {
    const float* x = (const float*)d_in[0];
    float* out = (float*)d_out;
    // B=64, F/FG=16 -> 1024 blocks
    softhist_kernel<<<dim3(64 * 16), dim3(256), 0, stream>>>(x, out);
}

// Round 2
// 23.390 us; speedup vs baseline: 1.1733x; 1.1733x over previous
//
#include <hip/hip_runtime.h>

// SoftHistogram: x[B=64, N=1000, F=256] fp32 -> out[B, F*K=2048] fp32
// out[b, f*8+k] = mean_n relu(1 - 16*|x[b,n,f] - (k+0.5)/8|)
// With u = 8x - 0.5:  y_k = relu(1 - 2*|u - k|).
//
// R2 change vs R1: per-block f-slice widened 16 -> 32 floats (128 B), so each
// wave-load reads 8 fully-consumed 128-B-aligned lines (R1 split every line
// across two blocks on different XCDs). Block = 512 threads (grid 512 = 2
// blocks/CU, 16 waves/CU). n-loop unrolled x2 for MLP.

__global__ __launch_bounds__(512) void softhist_kernel(const float* __restrict__ x,
                                                       float* __restrict__ out) {
    constexpr int N = 1000, F = 256, K = 8;
    constexpr int FG = 32;             // f's per block -> 128 B per row per block
    constexpr int NS = 64;             // n-subgroups
    constexpr int LSTR = FG * K + 1;   // 257: odd stride -> conflict-free column reads

    const int bid = blockIdx.x;
    const int b   = bid >> 3;          // / (F/FG)
    const int f0  = (bid & 7) * FG;

    const int t    = threadIdx.x;
    const int fl8  = t & 7;            // which float4 of the 32-f slice
    const int nsub = t >> 3;           // 0..63, n stride 64

    float acc[4][K];
#pragma unroll
    for (int i = 0; i < 4; ++i)
#pragma unroll
        for (int k = 0; k < K; ++k) acc[i][k] = 0.0f;

    const float* base = x + (size_t)b * N * F + f0 + fl8 * 4;

#define PROCESS(v)                                                        \
    {                                                                     \
        const float xs[4] = {(v).x, (v).y, (v).z, (v).w};                 \
        _Pragma("unroll")                                                 \
        for (int i = 0; i < 4; ++i) {                                     \
            const float u = fmaf(xs[i], 8.0f, -0.5f);                     \
            _Pragma("unroll")                                             \
            for (int k = 0; k < K; ++k) {                                 \
                const float y = fmaf(-2.0f, fabsf(u - (float)k), 1.0f);   \
                acc[i][k] += fmaxf(y, 0.0f);                              \
            }                                                             \
        }                                                                 \
    }

    int n = nsub;
    for (; n + NS < N; n += 2 * NS) {
        const float4 v0 = *reinterpret_cast<const float4*>(base + (size_t)n * F);
        const float4 v1 = *reinterpret_cast<const float4*>(base + (size_t)(n + NS) * F);
        PROCESS(v0);
        PROCESS(v1);
    }
    if (n < N) {
        const float4 v = *reinterpret_cast<const float4*>(base + (size_t)n * F);
        PROCESS(v);
    }
#undef PROCESS

    // LDS reduce across the 64 n-subgroups.
    // part[nsub][col], col = fl8*32 + i*8 + k in [0,256); row stride 257.
    __shared__ float part[NS * LSTR];
#pragma unroll
    for (int i = 0; i < 4; ++i)
#pragma unroll
        for (int k = 0; k < K; ++k)
            part[nsub * LSTR + fl8 * 32 + i * 8 + k] = acc[i][k];
    __syncthreads();

    if (t < FG * K) {  // 256 output columns per block
        float s = 0.0f;
#pragma unroll
        for (int ns = 0; ns < NS; ++ns) s += part[ns * LSTR + t];
        // col t = (fl8*4+i)*8 + k  ->  out[(b*F + f0 + lf)*K + k]
        out[(size_t)b * (F * K) + f0 * K + t] = s * (1.0f / (float)N);
    }
}

extern "C" void kernel_launch(void* const* d_in, const int* in_sizes, int n_in,
                              void* d_out, int out_size, void* d_ws, size_t ws_size,
                              hipStream_t stream) {
    const float* x = (const float*)d_in[0];
    float* out = (float*)d_out;
    // B=64 x (F/32)=8 -> 512 blocks of 512 threads
    softhist_kernel<<<dim3(64 * 8), dim3(512), 0, stream>>>(x, out);
}